// Round 1
// baseline (647.930 us; speedup 1.0000x reference)
//
#include <hip/hip_runtime.h>

// GatherLayer: out[b, :] = full_output[b, idx[b]*512 : (idx[b]+1)*512]
// BATCH=16384, OUTPUT_DIM=512, NB_ACTIONS=18.
// Pure memory-bound gather: 32 MB read + 32 MB write. float4-vectorized,
// fully coalesced (2 KB contiguous runs on both load and store sides).

#define BATCH 16384
#define OUTPUT_DIM 512
#define NB_ACTIONS 18
#define ROW_STRIDE (OUTPUT_DIM * NB_ACTIONS)   // 9216 floats per input row
#define VEC_PER_ROW (OUTPUT_DIM / 4)           // 128 float4 per output row

__global__ __launch_bounds__(256) void gather_kernel(
    const float4* __restrict__ in,   // [BATCH, ROW_STRIDE/4]
    const int*    __restrict__ idx,  // [BATCH]
    float4*       __restrict__ out)  // [BATCH, VEC_PER_ROW]
{
    const int total = BATCH * VEC_PER_ROW;  // 2,097,152 float4s
    for (int g = blockIdx.x * blockDim.x + threadIdx.x;
         g < total;
         g += gridDim.x * blockDim.x) {
        const int b  = g >> 7;        // g / VEC_PER_ROW
        const int d4 = g & 127;       // g % VEC_PER_ROW
        const int a  = idx[b];        // 0..17, shared by 128 consecutive threads
        // source float4 offset: b*ROW_STRIDE/4 + a*OUTPUT_DIM/4 + d4
        out[g] = in[b * (ROW_STRIDE / 4) + a * (OUTPUT_DIM / 4) + d4];
    }
}

extern "C" void kernel_launch(void* const* d_in, const int* in_sizes, int n_in,
                              void* d_out, int out_size, void* d_ws, size_t ws_size,
                              hipStream_t stream) {
    const float4* in  = (const float4*)d_in[0];
    const int*    idx = (const int*)d_in[1];
    float4*       out = (float4*)d_out;

    const int total  = BATCH * VEC_PER_ROW;        // 2,097,152
    const int block  = 256;
    int grid = (total + block - 1) / block;        // 8192 blocks
    gather_kernel<<<grid, block, 0, stream>>>(in, idx, out);
}